// Round 7
// baseline (151.484 us; speedup 1.0000x reference)
//
#include <hip/hip_runtime.h>

#define NB 196      // bins of 256 nodes: ceil(50000/256)
#define BSH 8       // bin shift
#define BMSK 255
#define NBLK_A 512  // phase-A blocks
#define BINCAP 6144 // max edges per bin (avg 4096, sigma 64 -> +32 sigma)

typedef __attribute__((ext_vector_type(8))) short short8;
typedef __attribute__((ext_vector_type(4))) float f32x4;
typedef __attribute__((ext_vector_type(4))) unsigned int u32x4;

static inline size_t alignup(size_t x) { return (x + 255) & ~(size_t)255; }

__device__ __forceinline__ unsigned short f2bf(float f) {  // RNE fp32->bf16
    unsigned int u = __float_as_uint(f);
    u = (u + 0x7fffu + ((u >> 16) & 1u)) >> 16;
    return (unsigned short)u;
}

// ---- phase A1: per-block bin histogram (blocks 0..511) + weight transpose (blocks 512+)
__global__ __launch_bounds__(256) void k_hist(const int* __restrict__ colp, int nE,
                                              unsigned* __restrict__ counts,
                                              const float* __restrict__ W1,
                                              const float* __restrict__ W2,
                                              unsigned short* __restrict__ Wt1,
                                              unsigned short* __restrict__ Wt2) {
    int blk = blockIdx.x;
    if (blk >= NBLK_A) {  // weight prep: Wt[n][k] = bf16(W[k][n])
        int i = (blk - NBLK_A) * 256 + threadIdx.x;
        if (i < 128 * 128) { int k = i >> 7, c = i & 127; Wt1[(size_t)c * 128 + k] = f2bf(W1[i]); }
        if (i < 128 * 64)  { int k = i >> 6, c = i & 63;  Wt2[(size_t)c * 128 + k] = f2bf(W2[i]); }
        return;
    }
    __shared__ unsigned h[NB];
    for (int i = threadIdx.x; i < NB; i += 256) h[i] = 0;
    __syncthreads();
    int chunk = (nE + NBLK_A - 1) / NBLK_A;
    int e0 = blk * chunk, e1 = min(nE, e0 + chunk);
    for (int e = e0 + (int)threadIdx.x; e < e1; e += 256)
        atomicAdd(&h[colp[e] >> BSH], 1u);
    __syncthreads();
    for (int i = threadIdx.x; i < NB; i += 256) counts[(size_t)i * NBLK_A + blk] = h[i];
}

// ---- phase A2a: exclusive scan of each bin's 512 per-block counts; bintot
__global__ __launch_bounds__(256) void k_scanA(unsigned* __restrict__ counts,
                                               unsigned* __restrict__ bintot) {
    int bin = blockIdx.x, t = threadIdx.x;
    __shared__ unsigned ps[256];
    unsigned c0 = counts[(size_t)bin * NBLK_A + 2 * t];
    unsigned c1 = counts[(size_t)bin * NBLK_A + 2 * t + 1];
    unsigned s = c0 + c1;
    ps[t] = s;
    __syncthreads();
    for (int d = 1; d < 256; d <<= 1) {
        unsigned v = (t >= d) ? ps[t - d] : 0u;
        __syncthreads();
        ps[t] += v;
        __syncthreads();
    }
    unsigned base = ps[t] - s;  // exclusive
    counts[(size_t)bin * NBLK_A + 2 * t] = base;
    counts[(size_t)bin * NBLK_A + 2 * t + 1] = base + c0;
    if (t == 255) bintot[bin] = ps[255];
}

// ---- phase A2b: bin bases (edgebase[NB] = nE)
__global__ __launch_bounds__(256) void k_scanB(const unsigned* __restrict__ bintot,
                                               unsigned* __restrict__ edgebase, int nE) {
    __shared__ unsigned bt[NB];
    int t = threadIdx.x;
    if (t < NB) bt[t] = bintot[t];
    __syncthreads();
    if (t == 0) {
        unsigned run = 0;
        for (int b = 0; b < NB; ++b) { unsigned v = bt[b]; bt[b] = run; run += v; }
    }
    __syncthreads();
    if (t < NB) edgebase[t] = bt[t];
    if (t == 0) edgebase[NB] = (unsigned)nE;
}

// ---- phase A3: scatter packed (row<<8 | col_low) into bin segments (dense runs)
__global__ __launch_bounds__(256) void k_scatter(const int* __restrict__ colp,
                                                 const int* __restrict__ rowp, int nE,
                                                 const unsigned* __restrict__ counts,
                                                 const unsigned* __restrict__ edgebase,
                                                 unsigned* __restrict__ pairs) {
    __shared__ unsigned cur[NB];
    int blk = blockIdx.x;
    for (int i = threadIdx.x; i < NB; i += 256)
        cur[i] = edgebase[i] + counts[(size_t)i * NBLK_A + blk];
    __syncthreads();
    int chunk = (nE + NBLK_A - 1) / NBLK_A;
    int e0 = blk * chunk, e1 = min(nE, e0 + chunk);
    for (int e = e0 + (int)threadIdx.x; e < e1; e += 256) {
        int c = colp[e], r = rowp[e];
        unsigned pos = atomicAdd(&cur[c >> BSH], 1u);
        pairs[pos] = ((unsigned)r << BSH) | (unsigned)(c & BMSK);
    }
}

// ---- phase B: per-bin CSR build in LDS; neighbor lists SORTED by src id
// (sorted adjacency -> convoy locality in gathers: all threads walk sources in
// ascending order, so the instantaneous working set is a sliding window that
// fits per-XCD L2 instead of the whole hs array). Also emits dis[].
__global__ __launch_bounds__(256) void k_binbuild(const unsigned* __restrict__ pairs,
                                                  const unsigned* __restrict__ edgebase,
                                                  unsigned* __restrict__ csr,
                                                  unsigned* __restrict__ off,
                                                  float* __restrict__ dis, int n) {
    __shared__ unsigned lp[BINCAP];
    __shared__ unsigned lr[BINCAP];
    __shared__ unsigned hist[256];
    __shared__ unsigned scn[256];
    int b = blockIdx.x, t = threadIdx.x;
    unsigned e0 = edgebase[b], e1 = edgebase[b + 1];
    unsigned ec = e1 - e0;
    if (ec > BINCAP) ec = BINCAP;
    hist[t] = 0;
    __syncthreads();
    for (unsigned i = t; i < ec; i += 256) {
        unsigned v = pairs[e0 + i];
        lp[i] = v;
        atomicAdd(&hist[v & BMSK], 1u);
    }
    __syncthreads();
    unsigned hv = hist[t];
    scn[t] = hv;
    __syncthreads();
    for (int d = 1; d < 256; d <<= 1) {
        unsigned v = (t >= d) ? scn[t - d] : 0u;
        __syncthreads();
        scn[t] += v;
        __syncthreads();
    }
    unsigned ex = scn[t] - hv;  // exclusive
    int node = (b << BSH) + t;
    if (node < n) {
        off[node] = e0 + ex;
        dis[node] = rsqrtf((float)(hv + 1));
    }
    if (b == NB - 1 && t == 0) off[n] = e1;  // sentinel = nE
    __syncthreads();
    scn[t] = ex;  // repurpose as cursor
    __syncthreads();
    for (unsigned i = t; i < ec; i += 256) {
        unsigned v = lp[i];
        unsigned pos = atomicAdd(&scn[v & BMSK], 1u);
        lr[pos] = v >> BSH;
    }
    __syncthreads();
    // insertion-sort this node's sublist lr[ex .. ex+hv) ascending (avg 16 entries)
    for (unsigned i = 1; i < hv; ++i) {
        unsigned key = lr[ex + i];
        int j = (int)i - 1;
        while (j >= 0 && lr[ex + j] > key) { lr[ex + j + 1] = lr[ex + j]; --j; }
        lr[ex + j + 1] = key;
    }
    __syncthreads();
    for (unsigned i = t; i < ec; i += 256) csr[e0 + i] = lr[i];
}

// ---------- MFMA GEMM body (LDS-free): out[m,:] = bf16( dis[m] * relu?(A[m,:]+bias) @ W )
template <int NT, bool IN_BF16, bool BIAS_RELU>
__device__ __forceinline__ void gemm_body(int bid, const void* __restrict__ Ap,
                                          const unsigned short* __restrict__ Wt,
                                          const float* __restrict__ bias,
                                          const float* __restrict__ dis,
                                          unsigned short* __restrict__ out, int M) {
    const int lane = threadIdx.x & 63;
    const int wave = threadIdx.x >> 6;
    const int m0 = bid * 64 + wave * 16;
    const int lrow = lane & 15;
    const int lk = lane >> 4;
    int arow = m0 + lrow;
    if (arow >= M) arow = M - 1;  // clamp; garbage rows never stored

    f32x4 acc[NT];
#pragma unroll
    for (int t = 0; t < NT; ++t) acc[t] = (f32x4){0.f, 0.f, 0.f, 0.f};

#pragma unroll
    for (int k0 = 0; k0 < 4; ++k0) {
        const int kb = k0 * 32 + lk * 8;
        short8 afrag;
        if (IN_BF16) {
            const unsigned short* A = (const unsigned short*)Ap;
            u32x4 v = *(const u32x4*)&A[(size_t)arow * 128 + kb];
#pragma unroll
            for (int q = 0; q < 4; ++q) {
                float lo = __uint_as_float(v[q] << 16);
                float hi = __uint_as_float(v[q] & 0xffff0000u);
                if (BIAS_RELU) {
                    lo = fmaxf(lo + bias[kb + 2 * q], 0.f);
                    hi = fmaxf(hi + bias[kb + 2 * q + 1], 0.f);
                }
                afrag[2 * q] = (short)f2bf(lo);
                afrag[2 * q + 1] = (short)f2bf(hi);
            }
        } else {
            const float* A = (const float*)Ap;
            const float* ap = &A[(size_t)arow * 128 + kb];
            f32x4 v0 = __builtin_nontemporal_load((const f32x4*)ap);
            f32x4 v1 = __builtin_nontemporal_load((const f32x4*)(ap + 4));
#pragma unroll
            for (int q = 0; q < 4; ++q) {
                afrag[q] = (short)f2bf(v0[q]);
                afrag[4 + q] = (short)f2bf(v1[q]);
            }
        }
#pragma unroll
        for (int t = 0; t < NT; ++t) {
            const int bcol = t * 16 + lrow;
            short8 bfrag = *(const short8*)&Wt[(size_t)bcol * 128 + kb];
            acc[t] = __builtin_amdgcn_mfma_f32_16x16x32_bf16(afrag, bfrag, acc[t], 0, 0, 0);
        }
    }

#pragma unroll
    for (int i = 0; i < 4; ++i) {
        int row = m0 + lk * 4 + i;
        if (row < M) {
            float s = dis[row];
#pragma unroll
            for (int t = 0; t < NT; ++t)
                out[(size_t)row * (NT * 16) + t * 16 + lrow] = f2bf(acc[t][i] * s);
        }
    }
}

__global__ __launch_bounds__(256) void k_gemm1(const float* __restrict__ x,
                                               const unsigned short* __restrict__ Wt1,
                                               const float* __restrict__ dis,
                                               unsigned short* __restrict__ hs1, int M) {
    gemm_body<8, false, false>(blockIdx.x, x, Wt1, nullptr, dis, hs1, M);
}

__global__ __launch_bounds__(256) void k_gemm2(const unsigned short* __restrict__ agg1,
                                               const unsigned short* __restrict__ Wt2,
                                               const float* __restrict__ b1,
                                               const float* __restrict__ dis,
                                               unsigned short* __restrict__ hs2, int M) {
    gemm_body<4, true, true>(blockIdx.x, agg1, Wt2, b1, dis, hs2, M);
}

__device__ __forceinline__ void acc8(float a[8], u32x4 u) {
    a[0] += __uint_as_float(u[0] << 16);
    a[1] += __uint_as_float(u[0] & 0xffff0000u);
    a[2] += __uint_as_float(u[1] << 16);
    a[3] += __uint_as_float(u[1] & 0xffff0000u);
    a[4] += __uint_as_float(u[2] << 16);
    a[5] += __uint_as_float(u[2] & 0xffff0000u);
    a[6] += __uint_as_float(u[3] << 16);
    a[7] += __uint_as_float(u[3] & 0xffff0000u);
}

// ---- CSR gather over pre-scaled rows (hs[r] = dis[r]*h[r]):
// res[v,:] = dis[v] * (hs[v,:] + sum_r hs[r,:]) (+bias). Neighbor lists sorted.
template <int D, bool OUT_F32, bool ADD_BIAS>
__global__ __launch_bounds__(256) void k_gather_csr(const unsigned short* __restrict__ hs,
                                                    const unsigned* __restrict__ csr,
                                                    const unsigned* __restrict__ off,
                                                    const float* __restrict__ dis,
                                                    const float* __restrict__ bias,
                                                    void* __restrict__ outp, int n) {
    const int TPN = D / 8;
    const int NPB = 256 / TPN;
    int v = blockIdx.x * NPB + (int)(threadIdx.x / TPN);
    int c = threadIdx.x % TPN;
    if (v >= n) return;
    const u32x4* h4 = (const u32x4*)hs;
    const size_t rs = D / 8;
    size_t base = (size_t)v * rs + c;

    unsigned s = off[v], e = off[v + 1];
    float dv = dis[v];

    float a[8];
#pragma unroll
    for (int j = 0; j < 8; ++j) a[j] = 0.f;
    acc8(a, h4[base]);  // self-loop (pre-scaled)

    unsigned i = s;
    for (; i + 4 <= e; i += 4) {
        unsigned r0 = csr[i], r1 = csr[i + 1], r2 = csr[i + 2], r3 = csr[i + 3];
        u32x4 m0 = h4[(size_t)r0 * rs + c];
        u32x4 m1 = h4[(size_t)r1 * rs + c];
        u32x4 m2 = h4[(size_t)r2 * rs + c];
        u32x4 m3 = h4[(size_t)r3 * rs + c];
        acc8(a, m0); acc8(a, m1); acc8(a, m2); acc8(a, m3);
    }
    for (; i < e; ++i) acc8(a, h4[(size_t)csr[i] * rs + c]);

    if (OUT_F32) {
        float* o = (float*)outp;
        float rr[8];
#pragma unroll
        for (int j = 0; j < 8; ++j) {
            rr[j] = a[j] * dv;
            if (ADD_BIAS) rr[j] += bias[c * 8 + j];
        }
        f32x4 lov = {rr[0], rr[1], rr[2], rr[3]};
        f32x4 hiv = {rr[4], rr[5], rr[6], rr[7]};
        __builtin_nontemporal_store(lov, (f32x4*)&o[(size_t)v * D + c * 8]);
        __builtin_nontemporal_store(hiv, (f32x4*)&o[(size_t)v * D + c * 8 + 4]);
    } else {
        u32x4 o;
        o[0] = (unsigned)f2bf(a[0] * dv) | ((unsigned)f2bf(a[1] * dv) << 16);
        o[1] = (unsigned)f2bf(a[2] * dv) | ((unsigned)f2bf(a[3] * dv) << 16);
        o[2] = (unsigned)f2bf(a[4] * dv) | ((unsigned)f2bf(a[5] * dv) << 16);
        o[3] = (unsigned)f2bf(a[6] * dv) | ((unsigned)f2bf(a[7] * dv) << 16);
        ((u32x4*)outp)[base] = o;  // cached store: gemm2 re-reads agg1
    }
}

extern "C" void kernel_launch(void* const* d_in, const int* in_sizes, int n_in,
                              void* d_out, int out_size, void* d_ws, size_t ws_size,
                              hipStream_t stream) {
    const float* x  = (const float*)d_in[0];
    const int*   ei = (const int*)d_in[1];
    const float* W1 = (const float*)d_in[2];
    const float* b1 = (const float*)d_in[3];
    const float* W2 = (const float*)d_in[4];
    const float* b2 = (const float*)d_in[5];

    const int Din = 128;
    const int Nn = in_sizes[0] / Din;   // 50000
    const int E  = in_sizes[1] / 2;     // 800000
    const int* rowp = ei;
    const int* colp = ei + E;

    char* ws = (char*)d_ws;
    size_t off_ = 0;
    unsigned*       counts   = (unsigned*)(ws + off_);       off_ = alignup(off_ + (size_t)NB * NBLK_A * 4);
    unsigned*       bintot   = (unsigned*)(ws + off_);       off_ = alignup(off_ + NB * 4);
    unsigned*       edgebase = (unsigned*)(ws + off_);       off_ = alignup(off_ + (NB + 1) * 4);
    unsigned*       pairs    = (unsigned*)(ws + off_);       off_ = alignup(off_ + (size_t)E * 4);
    unsigned*       csr      = (unsigned*)(ws + off_);       off_ = alignup(off_ + (size_t)E * 4);
    unsigned*       offv     = (unsigned*)(ws + off_);       off_ = alignup(off_ + (size_t)(Nn + 1) * 4);
    float*          dis      = (float*)(ws + off_);          off_ = alignup(off_ + (size_t)Nn * 4);
    unsigned short* Wt1      = (unsigned short*)(ws + off_); off_ = alignup(off_ + 128 * 128 * 2);
    unsigned short* Wt2      = (unsigned short*)(ws + off_); off_ = alignup(off_ + 128 * 64 * 2);
    unsigned short* hs1      = (unsigned short*)(ws + off_); off_ = alignup(off_ + (size_t)Nn * 128 * 2);
    unsigned short* agg1     = (unsigned short*)(ws + off_); off_ = alignup(off_ + (size_t)Nn * 128 * 2);
    unsigned short* hs2      = hs1;  // hs1 dead after gather1; reuse
    float*          outp     = (float*)d_out;

    // graph build: histogram -> scans -> scatter pairs -> per-bin sorted-CSR build
    k_hist<<<NBLK_A + 64, 256, 0, stream>>>(colp, E, counts, W1, W2, Wt1, Wt2);
    k_scanA<<<NB, 256, 0, stream>>>(counts, bintot);
    k_scanB<<<1, 256, 0, stream>>>(bintot, edgebase, E);
    k_scatter<<<NBLK_A, 256, 0, stream>>>(colp, rowp, E, counts, edgebase, pairs);
    k_binbuild<<<NB, 256, 0, stream>>>(pairs, edgebase, csr, offv, dis, Nn);

    // layer 1: hs1 = bf16( dis[m] * (x @ W1)[m] )   (pre-scaled rows)
    k_gemm1<<<(Nn + 63) / 64, 256, 0, stream>>>(x, Wt1, dis, hs1, Nn);

    // agg1 = bf16( dis[v] * (hs1[v] + sum hs1[r]) )
    k_gather_csr<128, false, false><<<(Nn + 15) / 16, 256, 0, stream>>>(
        hs1, csr, offv, dis, nullptr, agg1, Nn);

    // layer 2: hs2 = bf16( dis[m] * (relu(agg1 + b1) @ W2)[m] )
    k_gemm2<<<(Nn + 63) / 64, 256, 0, stream>>>(agg1, Wt2, b1, dis, hs2, Nn);

    // out = dis[v] * (hs2[v] + sum hs2[r]) + b2   (fp32)
    k_gather_csr<64, true, true><<<(Nn + 31) / 32, 256, 0, stream>>>(
        hs2, csr, offv, dis, b2, (void*)outp, Nn);
}

// Round 8
// 147.702 us; speedup vs baseline: 1.0256x; 1.0256x over previous
//
#include <hip/hip_runtime.h>

#define NB 196      // bins of 256 nodes: ceil(50000/256)
#define BSH 8       // bin shift
#define BMSK 255
#define NBLK_A 512  // phase-A blocks
#define BINCAP 6144 // max edges per bin (avg 4096, sigma 64 -> +32 sigma)
#define NRND 25     // ordered-scatter rounds: row>>11 chunks (50000/2048)

typedef __attribute__((ext_vector_type(8))) short short8;
typedef __attribute__((ext_vector_type(4))) float f32x4;
typedef __attribute__((ext_vector_type(4))) unsigned int u32x4;

static inline size_t alignup(size_t x) { return (x + 255) & ~(size_t)255; }

__device__ __forceinline__ unsigned short f2bf(float f) {  // RNE fp32->bf16
    unsigned int u = __float_as_uint(f);
    u = (u + 0x7fffu + ((u >> 16) & 1u)) >> 16;
    return (unsigned short)u;
}

// ---- phase A1: per-block bin histogram (blocks 0..511) + weight transpose (blocks 512+)
__global__ __launch_bounds__(256) void k_hist(const int* __restrict__ colp, int nE,
                                              unsigned* __restrict__ counts,
                                              const float* __restrict__ W1,
                                              const float* __restrict__ W2,
                                              unsigned short* __restrict__ Wt1,
                                              unsigned short* __restrict__ Wt2) {
    int blk = blockIdx.x;
    if (blk >= NBLK_A) {  // weight prep: Wt[n][k] = bf16(W[k][n])
        int i = (blk - NBLK_A) * 256 + threadIdx.x;
        if (i < 128 * 128) { int k = i >> 7, c = i & 127; Wt1[(size_t)c * 128 + k] = f2bf(W1[i]); }
        if (i < 128 * 64)  { int k = i >> 6, c = i & 63;  Wt2[(size_t)c * 128 + k] = f2bf(W2[i]); }
        return;
    }
    __shared__ unsigned h[NB];
    for (int i = threadIdx.x; i < NB; i += 256) h[i] = 0;
    __syncthreads();
    int chunk = (nE + NBLK_A - 1) / NBLK_A;
    int e0 = blk * chunk, e1 = min(nE, e0 + chunk);
    for (int e = e0 + (int)threadIdx.x; e < e1; e += 256)
        atomicAdd(&h[colp[e] >> BSH], 1u);
    __syncthreads();
    for (int i = threadIdx.x; i < NB; i += 256) counts[(size_t)i * NBLK_A + blk] = h[i];
}

// ---- phase A2a: exclusive scan of each bin's 512 per-block counts; bintot
__global__ __launch_bounds__(256) void k_scanA(unsigned* __restrict__ counts,
                                               unsigned* __restrict__ bintot) {
    int bin = blockIdx.x, t = threadIdx.x;
    __shared__ unsigned ps[256];
    unsigned c0 = counts[(size_t)bin * NBLK_A + 2 * t];
    unsigned c1 = counts[(size_t)bin * NBLK_A + 2 * t + 1];
    unsigned s = c0 + c1;
    ps[t] = s;
    __syncthreads();
    for (int d = 1; d < 256; d <<= 1) {
        unsigned v = (t >= d) ? ps[t - d] : 0u;
        __syncthreads();
        ps[t] += v;
        __syncthreads();
    }
    unsigned base = ps[t] - s;  // exclusive
    counts[(size_t)bin * NBLK_A + 2 * t] = base;
    counts[(size_t)bin * NBLK_A + 2 * t + 1] = base + c0;
    if (t == 255) bintot[bin] = ps[255];
}

// ---- phase A2b: bin bases (edgebase[NB] = nE)
__global__ __launch_bounds__(256) void k_scanB(const unsigned* __restrict__ bintot,
                                               unsigned* __restrict__ edgebase, int nE) {
    __shared__ unsigned bt[NB];
    int t = threadIdx.x;
    if (t < NB) bt[t] = bintot[t];
    __syncthreads();
    if (t == 0) {
        unsigned run = 0;
        for (int b = 0; b < NB; ++b) { unsigned v = bt[b]; bt[b] = run; run += v; }
    }
    __syncthreads();
    if (t < NB) edgebase[t] = bt[t];
    if (t == 0) edgebase[NB] = (unsigned)nE;
}

// ---- phase A3: scatter packed (row<<8 | col_low) into bin segments (dense runs)
__global__ __launch_bounds__(256) void k_scatter(const int* __restrict__ colp,
                                                 const int* __restrict__ rowp, int nE,
                                                 const unsigned* __restrict__ counts,
                                                 const unsigned* __restrict__ edgebase,
                                                 unsigned* __restrict__ pairs) {
    __shared__ unsigned cur[NB];
    int blk = blockIdx.x;
    for (int i = threadIdx.x; i < NB; i += 256)
        cur[i] = edgebase[i] + counts[(size_t)i * NBLK_A + blk];
    __syncthreads();
    int chunk = (nE + NBLK_A - 1) / NBLK_A;
    int e0 = blk * chunk, e1 = min(nE, e0 + chunk);
    for (int e = e0 + (int)threadIdx.x; e < e1; e += 256) {
        int c = colp[e], r = rowp[e];
        unsigned pos = atomicAdd(&cur[c >> BSH], 1u);
        pairs[pos] = ((unsigned)r << BSH) | (unsigned)(c & BMSK);
    }
}

// ---- phase B: per-bin CSR build in LDS; neighbor lists COARSELY ordered by src
// via NRND sequential scatter rounds over row-chunks (row>>11, 2048 rows):
// round r scatters only items with src-chunk r; cross-round order guarantees
// per-node lists ascend in 2048-row windows -> convoy locality in gathers
// (sliding working set fits per-XCD L2) at ~2us instead of a 42us full sort.
__global__ __launch_bounds__(256) void k_binbuild(const unsigned* __restrict__ pairs,
                                                  const unsigned* __restrict__ edgebase,
                                                  unsigned* __restrict__ csr,
                                                  unsigned* __restrict__ off,
                                                  float* __restrict__ dis, int n) {
    __shared__ unsigned lp[BINCAP];
    __shared__ unsigned lr[BINCAP];
    __shared__ unsigned hist[256];
    __shared__ unsigned scn[256];
    int b = blockIdx.x, t = threadIdx.x;
    unsigned e0 = edgebase[b], e1 = edgebase[b + 1];
    unsigned ec = e1 - e0;
    if (ec > BINCAP) ec = BINCAP;
    hist[t] = 0;
    __syncthreads();
    for (unsigned i = t; i < ec; i += 256) {
        unsigned v = pairs[e0 + i];
        lp[i] = v;
        atomicAdd(&hist[v & BMSK], 1u);
    }
    __syncthreads();
    unsigned hv = hist[t];
    scn[t] = hv;
    __syncthreads();
    for (int d = 1; d < 256; d <<= 1) {
        unsigned v = (t >= d) ? scn[t - d] : 0u;
        __syncthreads();
        scn[t] += v;
        __syncthreads();
    }
    unsigned ex = scn[t] - hv;  // exclusive
    int node = (b << BSH) + t;
    if (node < n) {
        off[node] = e0 + ex;
        dis[node] = rsqrtf((float)(hv + 1));
    }
    if (b == NB - 1 && t == 0) off[n] = e1;  // sentinel = nE
    __syncthreads();
    scn[t] = ex;  // repurpose as cursor
    __syncthreads();
    // ordered rounds: coarse row-sort for free (racy only WITHIN a 2048-row chunk)
    for (unsigned r = 0; r < NRND; ++r) {
        for (unsigned i = t; i < ec; i += 256) {
            unsigned v = lp[i];
            if ((v >> (BSH + 11)) == r) {
                unsigned pos = atomicAdd(&scn[v & BMSK], 1u);
                lr[pos] = v >> BSH;
            }
        }
        __syncthreads();
    }
    for (unsigned i = t; i < ec; i += 256) csr[e0 + i] = lr[i];
}

// ---------- MFMA GEMM (LDS-free): hs1[m,:] = bf16( dis[m] * (x[m,:] @ W1) )
__global__ __launch_bounds__(256) void k_gemm1(const float* __restrict__ x,
                                               const unsigned short* __restrict__ Wt1,
                                               const float* __restrict__ dis,
                                               unsigned short* __restrict__ hs1, int M) {
    const int NT = 8;
    const int lane = threadIdx.x & 63;
    const int wave = threadIdx.x >> 6;
    const int m0 = blockIdx.x * 64 + wave * 16;
    const int lrow = lane & 15;
    const int lk = lane >> 4;
    int arow = m0 + lrow;
    if (arow >= M) arow = M - 1;  // clamp; garbage rows never stored

    f32x4 acc[NT];
#pragma unroll
    for (int t = 0; t < NT; ++t) acc[t] = (f32x4){0.f, 0.f, 0.f, 0.f};

#pragma unroll
    for (int k0 = 0; k0 < 4; ++k0) {
        const int kb = k0 * 32 + lk * 8;
        const float* ap = &x[(size_t)arow * 128 + kb];
        f32x4 v0 = __builtin_nontemporal_load((const f32x4*)ap);
        f32x4 v1 = __builtin_nontemporal_load((const f32x4*)(ap + 4));
        short8 afrag;
#pragma unroll
        for (int q = 0; q < 4; ++q) {
            afrag[q] = (short)f2bf(v0[q]);
            afrag[4 + q] = (short)f2bf(v1[q]);
        }
#pragma unroll
        for (int t = 0; t < NT; ++t) {
            const int bcol = t * 16 + lrow;
            short8 bfrag = *(const short8*)&Wt1[(size_t)bcol * 128 + kb];
            acc[t] = __builtin_amdgcn_mfma_f32_16x16x32_bf16(afrag, bfrag, acc[t], 0, 0, 0);
        }
    }

#pragma unroll
    for (int i = 0; i < 4; ++i) {
        int row = m0 + lk * 4 + i;
        if (row < M) {
            float s = dis[row];
#pragma unroll
            for (int t = 0; t < NT; ++t)
                hs1[(size_t)row * 128 + t * 16 + lrow] = f2bf(acc[t][i] * s);
        }
    }
}

__device__ __forceinline__ void acc8(float a[8], u32x4 u) {
    a[0] += __uint_as_float(u[0] << 16);
    a[1] += __uint_as_float(u[0] & 0xffff0000u);
    a[2] += __uint_as_float(u[1] << 16);
    a[3] += __uint_as_float(u[1] & 0xffff0000u);
    a[4] += __uint_as_float(u[2] << 16);
    a[5] += __uint_as_float(u[2] & 0xffff0000u);
    a[6] += __uint_as_float(u[3] << 16);
    a[7] += __uint_as_float(u[3] & 0xffff0000u);
}

// ---- FUSED gather1 + bias + relu + GEMM2:
// block = 16 nodes (one MFMA row-tile). 16 threads/node gather 128-dim rows of
// pre-scaled hs1; apply dv, +b1, relu in regs; bf16 -> LDS (stride 136 vs bank
// conflicts); 4 waves MFMA x Wt2 (wave w -> out cols w*16..+16); store
// hs2[m,:] = bf16( dis[m] * tile ). Kills agg1 write+read and one launch.
__global__ __launch_bounds__(256) void k_fuse2(const unsigned short* __restrict__ hs1,
                                               const unsigned* __restrict__ csr,
                                               const unsigned* __restrict__ off,
                                               const float* __restrict__ dis,
                                               const float* __restrict__ b1,
                                               const unsigned short* __restrict__ Wt2,
                                               unsigned short* __restrict__ hs2, int n) {
    __shared__ unsigned short st[16 * 136];  // 16 rows x 128 bf16, stride 136
    const int tid = threadIdx.x;
    int vloc = tid >> 4;
    int c = tid & 15;  // 16B chunk (8 bf16)
    int v = blockIdx.x * 16 + vloc;
    if (v >= n) v = n - 1;  // clamp (grid exact for 50000)

    const u32x4* h4 = (const u32x4*)hs1;
    size_t base = (size_t)v * 16 + c;
    unsigned s = off[v], e = off[v + 1];
    float dv = dis[v];

    float a[8];
#pragma unroll
    for (int j = 0; j < 8; ++j) a[j] = 0.f;
    acc8(a, h4[base]);  // self-loop (pre-scaled)

    unsigned i = s;
    for (; i + 4 <= e; i += 4) {
        unsigned r0 = csr[i], r1 = csr[i + 1], r2 = csr[i + 2], r3 = csr[i + 3];
        u32x4 m0 = h4[(size_t)r0 * 16 + c];
        u32x4 m1 = h4[(size_t)r1 * 16 + c];
        u32x4 m2 = h4[(size_t)r2 * 16 + c];
        u32x4 m3 = h4[(size_t)r3 * 16 + c];
        acc8(a, m0); acc8(a, m1); acc8(a, m2); acc8(a, m3);
    }
    for (; i < e; ++i) acc8(a, h4[(size_t)csr[i] * 16 + c]);

    // agg -> +b1, relu, bf16 -> LDS row
    u32x4 pk;
#pragma unroll
    for (int q = 0; q < 4; ++q) {
        float lo = fmaxf(a[2 * q] * dv + b1[c * 8 + 2 * q], 0.f);
        float hi = fmaxf(a[2 * q + 1] * dv + b1[c * 8 + 2 * q + 1], 0.f);
        pk[q] = (unsigned)f2bf(lo) | ((unsigned)f2bf(hi) << 16);
    }
    *(u32x4*)&st[vloc * 136 + c * 8] = pk;
    __syncthreads();

    // MFMA: 4 waves, wave w handles out cols w*16..w*16+16
    const int lane = tid & 63;
    const int wave = tid >> 6;
    const int lrow = lane & 15;
    const int lk = lane >> 4;
    f32x4 acc = (f32x4){0.f, 0.f, 0.f, 0.f};
#pragma unroll
    for (int k0 = 0; k0 < 4; ++k0) {
        const int kb = k0 * 32 + lk * 8;
        short8 afrag = *(const short8*)&st[lrow * 136 + kb];
        const int bcol = wave * 16 + lrow;
        short8 bfrag = *(const short8*)&Wt2[(size_t)bcol * 128 + kb];
        acc = __builtin_amdgcn_mfma_f32_16x16x32_bf16(afrag, bfrag, acc, 0, 0, 0);
    }
#pragma unroll
    for (int i2 = 0; i2 < 4; ++i2) {
        int row = blockIdx.x * 16 + lk * 4 + i2;
        if (row < n) {
            float sc = dis[row];
            hs2[(size_t)row * 64 + wave * 16 + lrow] = f2bf(acc[i2] * sc);
        }
    }
}

// ---- gather2 over pre-scaled hs2: out[v,:] = dis[v]*(hs2[v]+sum hs2[r]) + b2 (fp32)
__global__ __launch_bounds__(256) void k_gather2(const unsigned short* __restrict__ hs,
                                                 const unsigned* __restrict__ csr,
                                                 const unsigned* __restrict__ off,
                                                 const float* __restrict__ dis,
                                                 const float* __restrict__ bias,
                                                 float* __restrict__ outp, int n) {
    int v = blockIdx.x * 32 + (int)(threadIdx.x >> 3);
    int c = threadIdx.x & 7;
    if (v >= n) return;
    const u32x4* h4 = (const u32x4*)hs;
    size_t base = (size_t)v * 8 + c;

    unsigned s = off[v], e = off[v + 1];
    float dv = dis[v];

    float a[8];
#pragma unroll
    for (int j = 0; j < 8; ++j) a[j] = 0.f;
    acc8(a, h4[base]);  // self-loop (pre-scaled)

    unsigned i = s;
    for (; i + 4 <= e; i += 4) {
        unsigned r0 = csr[i], r1 = csr[i + 1], r2 = csr[i + 2], r3 = csr[i + 3];
        u32x4 m0 = h4[(size_t)r0 * 8 + c];
        u32x4 m1 = h4[(size_t)r1 * 8 + c];
        u32x4 m2 = h4[(size_t)r2 * 8 + c];
        u32x4 m3 = h4[(size_t)r3 * 8 + c];
        acc8(a, m0); acc8(a, m1); acc8(a, m2); acc8(a, m3);
    }
    for (; i < e; ++i) acc8(a, h4[(size_t)csr[i] * 8 + c]);

    float rr[8];
#pragma unroll
    for (int j = 0; j < 8; ++j) rr[j] = a[j] * dv + bias[c * 8 + j];
    f32x4 lov = {rr[0], rr[1], rr[2], rr[3]};
    f32x4 hiv = {rr[4], rr[5], rr[6], rr[7]};
    __builtin_nontemporal_store(lov, (f32x4*)&outp[(size_t)v * 64 + c * 8]);
    __builtin_nontemporal_store(hiv, (f32x4*)&outp[(size_t)v * 64 + c * 8 + 4]);
}

extern "C" void kernel_launch(void* const* d_in, const int* in_sizes, int n_in,
                              void* d_out, int out_size, void* d_ws, size_t ws_size,
                              hipStream_t stream) {
    const float* x  = (const float*)d_in[0];
    const int*   ei = (const int*)d_in[1];
    const float* W1 = (const float*)d_in[2];
    const float* b1 = (const float*)d_in[3];
    const float* W2 = (const float*)d_in[4];
    const float* b2 = (const float*)d_in[5];

    const int Din = 128;
    const int Nn = in_sizes[0] / Din;   // 50000
    const int E  = in_sizes[1] / 2;     // 800000
    const int* rowp = ei;
    const int* colp = ei + E;

    char* ws = (char*)d_ws;
    size_t off_ = 0;
    unsigned*       counts   = (unsigned*)(ws + off_);       off_ = alignup(off_ + (size_t)NB * NBLK_A * 4);
    unsigned*       bintot   = (unsigned*)(ws + off_);       off_ = alignup(off_ + NB * 4);
    unsigned*       edgebase = (unsigned*)(ws + off_);       off_ = alignup(off_ + (NB + 1) * 4);
    unsigned*       pairs    = (unsigned*)(ws + off_);       off_ = alignup(off_ + (size_t)E * 4);
    unsigned*       csr      = (unsigned*)(ws + off_);       off_ = alignup(off_ + (size_t)E * 4);
    unsigned*       offv     = (unsigned*)(ws + off_);       off_ = alignup(off_ + (size_t)(Nn + 1) * 4);
    float*          dis      = (float*)(ws + off_);          off_ = alignup(off_ + (size_t)Nn * 4);
    unsigned short* Wt1      = (unsigned short*)(ws + off_); off_ = alignup(off_ + 128 * 128 * 2);
    unsigned short* Wt2      = (unsigned short*)(ws + off_); off_ = alignup(off_ + 128 * 64 * 2);
    unsigned short* hs1      = (unsigned short*)(ws + off_); off_ = alignup(off_ + (size_t)Nn * 128 * 2);
    unsigned short* hs2      = (unsigned short*)(ws + off_); off_ = alignup(off_ + (size_t)Nn * 64 * 2);
    float*          outp     = (float*)d_out;

    // graph build: histogram -> scans -> scatter pairs -> per-bin coarse-sorted CSR
    k_hist<<<NBLK_A + 64, 256, 0, stream>>>(colp, E, counts, W1, W2, Wt1, Wt2);
    k_scanA<<<NB, 256, 0, stream>>>(counts, bintot);
    k_scanB<<<1, 256, 0, stream>>>(bintot, edgebase, E);
    k_scatter<<<NBLK_A, 256, 0, stream>>>(colp, rowp, E, counts, edgebase, pairs);
    k_binbuild<<<NB, 256, 0, stream>>>(pairs, edgebase, csr, offv, dis, Nn);

    // layer 1: hs1 = bf16( dis[m] * (x @ W1)[m] )   (pre-scaled rows)
    k_gemm1<<<(Nn + 63) / 64, 256, 0, stream>>>(x, Wt1, dis, hs1, Nn);

    // fused: gather1 + b1 + relu + GEMM2 -> hs2 = bf16( dis[m] * (relu(agg1+b1) @ W2)[m] )
    k_fuse2<<<(Nn + 15) / 16, 256, 0, stream>>>(hs1, csr, offv, dis, b1, Wt2, hs2, Nn);

    // out = dis[v] * (hs2[v] + sum hs2[r]) + b2   (fp32)
    k_gather2<<<(Nn + 31) / 32, 256, 0, stream>>>(hs2, csr, offv, dis, b2, outp, Nn);
}

// Round 9
// 122.148 us; speedup vs baseline: 1.2402x; 1.2092x over previous
//
#include <hip/hip_runtime.h>

#define BSH 7        // col-bin shift: 128 nodes per bin
#define BMSK 127
#define NB 391       // ceil(50000/128)
#define ROWSH 13     // row-chunk shift: 8192 rows (hs window 2MB, fits XCD L2)
#define RCH 7        // ceil(50000/8192)
#define SEG (NB * RCH)   // 2737 segments
#define NBLK 128     // phase-A edge blocks
#define BINCAP 3072  // max edges per 128-node bin (avg 2048, sigma 45)

typedef __attribute__((ext_vector_type(8))) short short8;
typedef __attribute__((ext_vector_type(4))) float f32x4;
typedef __attribute__((ext_vector_type(4))) unsigned int u32x4;

static inline size_t alignup(size_t x) { return (x + 255) & ~(size_t)255; }

__device__ __forceinline__ unsigned short f2bf(float f) {  // RNE fp32->bf16
    unsigned int u = __float_as_uint(f);
    u = (u + 0x7fffu + ((u >> 16) & 1u)) >> 16;
    return (unsigned short)u;
}

// ---- A1: per-block 2-level histogram (blocks 0..NBLK-1) + weight prep (blocks NBLK+)
__global__ __launch_bounds__(256) void k_hist(const int* __restrict__ colp,
                                              const int* __restrict__ rowp, int nE,
                                              unsigned* __restrict__ counts,
                                              const float* __restrict__ W1,
                                              const float* __restrict__ W2,
                                              unsigned short* __restrict__ Wt1,
                                              unsigned short* __restrict__ Wt2) {
    int blk = blockIdx.x;
    if (blk >= NBLK) {  // weight prep: Wt[n][k] = bf16(W[k][n])
        int i = (blk - NBLK) * 256 + threadIdx.x;
        if (i < 128 * 128) { int k = i >> 7, c = i & 127; Wt1[(size_t)c * 128 + k] = f2bf(W1[i]); }
        if (i < 128 * 64)  { int k = i >> 6, c = i & 63;  Wt2[(size_t)c * 128 + k] = f2bf(W2[i]); }
        return;
    }
    __shared__ unsigned h[SEG];
    for (int i = threadIdx.x; i < SEG; i += 256) h[i] = 0;
    __syncthreads();
    int chunk = (nE + NBLK - 1) / NBLK;
    int e0 = blk * chunk, e1 = min(nE, e0 + chunk);
    for (int e = e0 + (int)threadIdx.x; e < e1; e += 256) {
        int c = colp[e], r = rowp[e];
        atomicAdd(&h[(c >> BSH) * RCH + (r >> ROWSH)], 1u);
    }
    __syncthreads();
    for (int i = threadIdx.x; i < SEG; i += 256) counts[(size_t)i * NBLK + blk] = h[i];
}

// ---- A2a: exclusive scan of each segment's NBLK per-block counts; segtot
__global__ __launch_bounds__(128) void k_scanA(unsigned* __restrict__ counts,
                                               unsigned* __restrict__ segtot) {
    int seg = blockIdx.x, t = threadIdx.x;
    __shared__ unsigned ps[NBLK];
    unsigned s = counts[(size_t)seg * NBLK + t];
    ps[t] = s;
    __syncthreads();
    for (int d = 1; d < NBLK; d <<= 1) {
        unsigned v = (t >= d) ? ps[t - d] : 0u;
        __syncthreads();
        ps[t] += v;
        __syncthreads();
    }
    counts[(size_t)seg * NBLK + t] = ps[t] - s;  // exclusive
    if (t == NBLK - 1) segtot[seg] = ps[NBLK - 1];
}

// ---- A2b: exclusive scan of segment totals -> segbase; bin edgebase
__global__ __launch_bounds__(256) void k_scanB(const unsigned* __restrict__ segtot,
                                               unsigned* __restrict__ segbase,
                                               unsigned* __restrict__ edgebase, int nE) {
    __shared__ unsigned ls[SEG];
    __shared__ unsigned ts[256];
    int t = threadIdx.x;
    for (int i = t; i < SEG; i += 256) ls[i] = segtot[i];
    __syncthreads();
    const int CH = (SEG + 255) / 256;
    unsigned s = 0;
#pragma unroll
    for (int j = 0; j < CH; ++j) {
        int idx = t * CH + j;
        if (idx < SEG) s += ls[idx];
    }
    ts[t] = s;
    __syncthreads();
    for (int d = 1; d < 256; d <<= 1) {
        unsigned v = (t >= d) ? ts[t - d] : 0u;
        __syncthreads();
        ts[t] += v;
        __syncthreads();
    }
    unsigned run = ts[t] - s;  // exclusive
    unsigned loc[CH > 0 ? CH : 1];
#pragma unroll
    for (int j = 0; j < CH; ++j) {
        int idx = t * CH + j;
        if (idx < SEG) { unsigned v = ls[idx]; loc[j] = run; segbase[idx] = run; run += v; }
    }
    __syncthreads();
#pragma unroll
    for (int j = 0; j < CH; ++j) {
        int idx = t * CH + j;
        if (idx < SEG) ls[idx] = loc[j];
    }
    __syncthreads();
    for (int b = t; b < NB; b += 256) edgebase[b] = ls[b * RCH];
    if (t == 0) edgebase[NB] = (unsigned)nE;
}

// ---- A3: scatter packed (row<<7 | col_low7) to position (bin, chunk, blk, ~) —
// pairs end up sorted by (bin, row-chunk) BY CONSTRUCTION (races only permute
// within a (seg,blk) run) -> convoy locality in gathers at zero sort cost.
__global__ __launch_bounds__(256) void k_scatter(const int* __restrict__ colp,
                                                 const int* __restrict__ rowp, int nE,
                                                 const unsigned* __restrict__ counts,
                                                 const unsigned* __restrict__ segbase,
                                                 unsigned* __restrict__ pairs) {
    __shared__ unsigned cur[SEG];
    int blk = blockIdx.x;
    for (int i = threadIdx.x; i < SEG; i += 256)
        cur[i] = segbase[i] + counts[(size_t)i * NBLK + blk];
    __syncthreads();
    int chunk = (nE + NBLK - 1) / NBLK;
    int e0 = blk * chunk, e1 = min(nE, e0 + chunk);
    for (int e = e0 + (int)threadIdx.x; e < e1; e += 256) {
        int c = colp[e], r = rowp[e];
        unsigned pos = atomicAdd(&cur[(c >> BSH) * RCH + (r >> ROWSH)], 1u);
        pairs[pos] = ((unsigned)r << BSH) | (unsigned)(c & BMSK);
    }
}

// ---- B: per-bin CSR build in LDS, single pass (strided read preserves the
// constructed chunk order to +-256-item fuzz). 128-node bins -> 391 blocks,
// 26KB LDS: 4x the occupancy of the 256-node variant.
__global__ __launch_bounds__(256) void k_binbuild(const unsigned* __restrict__ pairs,
                                                  const unsigned* __restrict__ edgebase,
                                                  unsigned* __restrict__ csr,
                                                  unsigned* __restrict__ off,
                                                  float* __restrict__ dis, int n) {
    __shared__ unsigned lp[BINCAP];
    __shared__ unsigned lr[BINCAP];
    __shared__ unsigned hist[128];
    __shared__ unsigned scn[128];
    int b = blockIdx.x, t = threadIdx.x;
    unsigned e0 = edgebase[b], e1 = edgebase[b + 1];
    unsigned ec = e1 - e0;
    if (ec > BINCAP) ec = BINCAP;
    if (t < 128) hist[t] = 0;
    __syncthreads();
    for (unsigned i = t; i < ec; i += 256) {
        unsigned v = pairs[e0 + i];
        lp[i] = v;
        atomicAdd(&hist[v & BMSK], 1u);
    }
    __syncthreads();
    unsigned hv = (t < 128) ? hist[t] : 0u;
    if (t < 128) scn[t] = hv;
    __syncthreads();
    for (int d = 1; d < 128; d <<= 1) {
        unsigned v = (t < 128 && t >= d) ? scn[t - d] : 0u;
        __syncthreads();
        if (t < 128) scn[t] += v;
        __syncthreads();
    }
    unsigned ex = (t < 128) ? scn[t] - hv : 0u;  // exclusive
    int node = (b << BSH) + t;
    if (t < 128 && node < n) {
        off[node] = e0 + ex;
        dis[node] = rsqrtf((float)(hv + 1));
    }
    if (b == NB - 1 && t == 0) off[n] = e1;  // sentinel = nE
    __syncthreads();
    if (t < 128) scn[t] = ex;  // repurpose as cursor
    __syncthreads();
    for (unsigned i = t; i < ec; i += 256) {
        unsigned v = lp[i];
        unsigned pos = atomicAdd(&scn[v & BMSK], 1u);
        lr[pos] = v >> BSH;
    }
    __syncthreads();
    for (unsigned i = t; i < ec; i += 256) csr[e0 + i] = lr[i];
}

// ---------- MFMA GEMM (LDS-free): hs1[m,:] = bf16( dis[m] * (x[m,:] @ W1) )
__global__ __launch_bounds__(256) void k_gemm1(const float* __restrict__ x,
                                               const unsigned short* __restrict__ Wt1,
                                               const float* __restrict__ dis,
                                               unsigned short* __restrict__ hs1, int M) {
    const int NT = 8;
    const int lane = threadIdx.x & 63;
    const int wave = threadIdx.x >> 6;
    const int m0 = blockIdx.x * 64 + wave * 16;
    const int lrow = lane & 15;
    const int lk = lane >> 4;
    int arow = m0 + lrow;
    if (arow >= M) arow = M - 1;  // clamp; garbage rows never stored

    f32x4 acc[NT];
#pragma unroll
    for (int t = 0; t < NT; ++t) acc[t] = (f32x4){0.f, 0.f, 0.f, 0.f};

#pragma unroll
    for (int k0 = 0; k0 < 4; ++k0) {
        const int kb = k0 * 32 + lk * 8;
        const float* ap = &x[(size_t)arow * 128 + kb];
        f32x4 v0 = __builtin_nontemporal_load((const f32x4*)ap);
        f32x4 v1 = __builtin_nontemporal_load((const f32x4*)(ap + 4));
        short8 afrag;
#pragma unroll
        for (int q = 0; q < 4; ++q) {
            afrag[q] = (short)f2bf(v0[q]);
            afrag[4 + q] = (short)f2bf(v1[q]);
        }
#pragma unroll
        for (int t = 0; t < NT; ++t) {
            const int bcol = t * 16 + lrow;
            short8 bfrag = *(const short8*)&Wt1[(size_t)bcol * 128 + kb];
            acc[t] = __builtin_amdgcn_mfma_f32_16x16x32_bf16(afrag, bfrag, acc[t], 0, 0, 0);
        }
    }

#pragma unroll
    for (int i = 0; i < 4; ++i) {
        int row = m0 + lk * 4 + i;
        if (row < M) {
            float s = dis[row];
#pragma unroll
            for (int t = 0; t < NT; ++t)
                hs1[(size_t)row * 128 + t * 16 + lrow] = f2bf(acc[t][i] * s);
        }
    }
}

__device__ __forceinline__ void acc8(float a[8], u32x4 u) {
    a[0] += __uint_as_float(u[0] << 16);
    a[1] += __uint_as_float(u[0] & 0xffff0000u);
    a[2] += __uint_as_float(u[1] << 16);
    a[3] += __uint_as_float(u[1] & 0xffff0000u);
    a[4] += __uint_as_float(u[2] << 16);
    a[5] += __uint_as_float(u[2] & 0xffff0000u);
    a[6] += __uint_as_float(u[3] << 16);
    a[7] += __uint_as_float(u[3] & 0xffff0000u);
}

// ---- FUSED gather1 + bias + relu + GEMM2 (block = 16 nodes = one MFMA row-tile)
__global__ __launch_bounds__(256) void k_fuse2(const unsigned short* __restrict__ hs1,
                                               const unsigned* __restrict__ csr,
                                               const unsigned* __restrict__ off,
                                               const float* __restrict__ dis,
                                               const float* __restrict__ b1,
                                               const unsigned short* __restrict__ Wt2,
                                               unsigned short* __restrict__ hs2, int n) {
    __shared__ unsigned short st[16 * 136];  // 16 rows x 128 bf16, stride 136
    const int tid = threadIdx.x;
    int vloc = tid >> 4;
    int c = tid & 15;  // 16B chunk (8 bf16)
    int v = blockIdx.x * 16 + vloc;
    if (v >= n) v = n - 1;  // clamp

    const u32x4* h4 = (const u32x4*)hs1;
    size_t base = (size_t)v * 16 + c;
    unsigned s = off[v], e = off[v + 1];
    float dv = dis[v];

    float a[8];
#pragma unroll
    for (int j = 0; j < 8; ++j) a[j] = 0.f;
    acc8(a, h4[base]);  // self-loop (pre-scaled)

    unsigned i = s;
    for (; i + 4 <= e; i += 4) {
        unsigned r0 = csr[i], r1 = csr[i + 1], r2 = csr[i + 2], r3 = csr[i + 3];
        u32x4 m0 = h4[(size_t)r0 * 16 + c];
        u32x4 m1 = h4[(size_t)r1 * 16 + c];
        u32x4 m2 = h4[(size_t)r2 * 16 + c];
        u32x4 m3 = h4[(size_t)r3 * 16 + c];
        acc8(a, m0); acc8(a, m1); acc8(a, m2); acc8(a, m3);
    }
    for (; i < e; ++i) acc8(a, h4[(size_t)csr[i] * 16 + c]);

    u32x4 pk;
#pragma unroll
    for (int q = 0; q < 4; ++q) {
        float lo = fmaxf(a[2 * q] * dv + b1[c * 8 + 2 * q], 0.f);
        float hi = fmaxf(a[2 * q + 1] * dv + b1[c * 8 + 2 * q + 1], 0.f);
        pk[q] = (unsigned)f2bf(lo) | ((unsigned)f2bf(hi) << 16);
    }
    *(u32x4*)&st[vloc * 136 + c * 8] = pk;
    __syncthreads();

    const int lane = tid & 63;
    const int wave = tid >> 6;
    const int lrow = lane & 15;
    const int lk = lane >> 4;
    f32x4 acc = (f32x4){0.f, 0.f, 0.f, 0.f};
#pragma unroll
    for (int k0 = 0; k0 < 4; ++k0) {
        const int kb = k0 * 32 + lk * 8;
        short8 afrag = *(const short8*)&st[lrow * 136 + kb];
        const int bcol = wave * 16 + lrow;
        short8 bfrag = *(const short8*)&Wt2[(size_t)bcol * 128 + kb];
        acc = __builtin_amdgcn_mfma_f32_16x16x32_bf16(afrag, bfrag, acc, 0, 0, 0);
    }
#pragma unroll
    for (int i2 = 0; i2 < 4; ++i2) {
        int row = blockIdx.x * 16 + lk * 4 + i2;
        if (row < n) {
            float sc = dis[row];
            hs2[(size_t)row * 64 + wave * 16 + lrow] = f2bf(acc[i2] * sc);
        }
    }
}

// ---- gather2 over pre-scaled hs2: out[v,:] = dis[v]*(hs2[v]+sum hs2[r]) + b2 (fp32)
__global__ __launch_bounds__(256) void k_gather2(const unsigned short* __restrict__ hs,
                                                 const unsigned* __restrict__ csr,
                                                 const unsigned* __restrict__ off,
                                                 const float* __restrict__ dis,
                                                 const float* __restrict__ bias,
                                                 float* __restrict__ outp, int n) {
    int v = blockIdx.x * 32 + (int)(threadIdx.x >> 3);
    int c = threadIdx.x & 7;
    if (v >= n) return;
    const u32x4* h4 = (const u32x4*)hs;
    size_t base = (size_t)v * 8 + c;

    unsigned s = off[v], e = off[v + 1];
    float dv = dis[v];

    float a[8];
#pragma unroll
    for (int j = 0; j < 8; ++j) a[j] = 0.f;
    acc8(a, h4[base]);  // self-loop (pre-scaled)

    unsigned i = s;
    for (; i + 4 <= e; i += 4) {
        unsigned r0 = csr[i], r1 = csr[i + 1], r2 = csr[i + 2], r3 = csr[i + 3];
        u32x4 m0 = h4[(size_t)r0 * 8 + c];
        u32x4 m1 = h4[(size_t)r1 * 8 + c];
        u32x4 m2 = h4[(size_t)r2 * 8 + c];
        u32x4 m3 = h4[(size_t)r3 * 8 + c];
        acc8(a, m0); acc8(a, m1); acc8(a, m2); acc8(a, m3);
    }
    for (; i < e; ++i) acc8(a, h4[(size_t)csr[i] * 8 + c]);

    float rr[8];
#pragma unroll
    for (int j = 0; j < 8; ++j) rr[j] = a[j] * dv + bias[c * 8 + j];
    f32x4 lov = {rr[0], rr[1], rr[2], rr[3]};
    f32x4 hiv = {rr[4], rr[5], rr[6], rr[7]};
    __builtin_nontemporal_store(lov, (f32x4*)&outp[(size_t)v * 64 + c * 8]);
    __builtin_nontemporal_store(hiv, (f32x4*)&outp[(size_t)v * 64 + c * 8 + 4]);
}

extern "C" void kernel_launch(void* const* d_in, const int* in_sizes, int n_in,
                              void* d_out, int out_size, void* d_ws, size_t ws_size,
                              hipStream_t stream) {
    const float* x  = (const float*)d_in[0];
    const int*   ei = (const int*)d_in[1];
    const float* W1 = (const float*)d_in[2];
    const float* b1 = (const float*)d_in[3];
    const float* W2 = (const float*)d_in[4];
    const float* b2 = (const float*)d_in[5];

    const int Din = 128;
    const int Nn = in_sizes[0] / Din;   // 50000
    const int E  = in_sizes[1] / 2;     // 800000
    const int* rowp = ei;
    const int* colp = ei + E;

    char* ws = (char*)d_ws;
    size_t off_ = 0;
    unsigned*       counts   = (unsigned*)(ws + off_);       off_ = alignup(off_ + (size_t)SEG * NBLK * 4);
    unsigned*       segtot   = (unsigned*)(ws + off_);       off_ = alignup(off_ + (size_t)SEG * 4);
    unsigned*       segbase  = (unsigned*)(ws + off_);       off_ = alignup(off_ + (size_t)SEG * 4);
    unsigned*       edgebase = (unsigned*)(ws + off_);       off_ = alignup(off_ + (size_t)(NB + 1) * 4);
    unsigned*       pairs    = (unsigned*)(ws + off_);       off_ = alignup(off_ + (size_t)E * 4);
    unsigned*       csr      = (unsigned*)(ws + off_);       off_ = alignup(off_ + (size_t)E * 4);
    unsigned*       offv     = (unsigned*)(ws + off_);       off_ = alignup(off_ + (size_t)(Nn + 1) * 4);
    float*          dis      = (float*)(ws + off_);          off_ = alignup(off_ + (size_t)Nn * 4);
    unsigned short* Wt1      = (unsigned short*)(ws + off_); off_ = alignup(off_ + 128 * 128 * 2);
    unsigned short* Wt2      = (unsigned short*)(ws + off_); off_ = alignup(off_ + 128 * 64 * 2);
    unsigned short* hs1      = (unsigned short*)(ws + off_); off_ = alignup(off_ + (size_t)Nn * 128 * 2);
    unsigned short* hs2      = (unsigned short*)(ws + off_); off_ = alignup(off_ + (size_t)Nn * 64 * 2);
    float*          outp     = (float*)d_out;

    // build: 2-level hist -> scans (positions encode (bin,chunk) order) -> scatter -> bin CSR
    k_hist<<<NBLK + 64, 256, 0, stream>>>(colp, rowp, E, counts, W1, W2, Wt1, Wt2);
    k_scanA<<<SEG, NBLK, 0, stream>>>(counts, segtot);
    k_scanB<<<1, 256, 0, stream>>>(segtot, segbase, edgebase, E);
    k_scatter<<<NBLK, 256, 0, stream>>>(colp, rowp, E, counts, segbase, pairs);
    k_binbuild<<<NB, 256, 0, stream>>>(pairs, edgebase, csr, offv, dis, Nn);

    // layer 1: hs1 = bf16( dis[m] * (x @ W1)[m] )
    k_gemm1<<<(Nn + 63) / 64, 256, 0, stream>>>(x, Wt1, dis, hs1, Nn);

    // fused: gather1 + b1 + relu + GEMM2 -> hs2 = bf16( dis[m] * (relu(agg1+b1) @ W2)[m] )
    k_fuse2<<<(Nn + 15) / 16, 256, 0, stream>>>(hs1, csr, offv, dis, b1, Wt2, hs2, Nn);

    // out = dis[v] * (hs2[v] + sum hs2[r]) + b2   (fp32)
    k_gather2<<<(Nn + 31) / 32, 256, 0, stream>>>(hs2, csr, offv, dis, b2, outp, Nn);
}